// Round 1
// baseline (484.329 us; speedup 1.0000x reference)
//
#include <hip/hip_runtime.h>

#define NG 32
#define NODES 4096
#define NTOT (NG * NODES)      // 131072
#define DIN 128
#define HID 16
#define ODIM 39
#define NEDGE (NTOT * 32)      // 4194304

// ws layout (floats)
#define WS_XL  0
#define WS_XR  (NTOT * HID)
#define WS_AGG (2 * NTOT * HID)
#define WS_CNT (3 * NTOT * HID)
// total floats: 3*NTOT*HID + NTOT = 6422528  (~24.5 MB)

// ---------------------------------------------------------------------------
// k1: xl = x @ Wl^T, xr = x @ Wr^T   (fused, one pass over x)
// 64-node tile in LDS; thread t: o = t&15 (output), ngrp = t>>4; 4 nodes/thread.
// ---------------------------------------------------------------------------
__global__ __launch_bounds__(256) void k1_lin(const float* __restrict__ x,
                                              const float* __restrict__ Wl,
                                              const float* __restrict__ Wr,
                                              float* __restrict__ xl,
                                              float* __restrict__ xr) {
    __shared__ float xs[64 * 132];   // pad 128->132: conflict-free b128 reads
    __shared__ float wls[16 * 132];
    __shared__ float wrs[16 * 132];
    const int t = threadIdx.x;

    // load W_l, W_r (2048 floats each = 512 float4)
    #pragma unroll
    for (int i = 0; i < 2; ++i) {
        int f = i * 256 + t;          // 0..511
        int o = f >> 5, k4 = f & 31;
        float4 a = reinterpret_cast<const float4*>(Wl)[f];
        float4 b = reinterpret_cast<const float4*>(Wr)[f];
        *reinterpret_cast<float4*>(&wls[o * 132 + 4 * k4]) = a;
        *reinterpret_cast<float4*>(&wrs[o * 132 + 4 * k4]) = b;
    }

    const long base = (long)blockIdx.x * 64;   // node base, grid = NTOT/64
    const float4* xg = reinterpret_cast<const float4*>(x) + base * 32; // 32 float4 per row
    #pragma unroll
    for (int i = 0; i < 8; ++i) {
        int f = i * 256 + t;          // 0..2047
        int n = f >> 5, k4 = f & 31;
        *reinterpret_cast<float4*>(&xs[n * 132 + 4 * k4]) = xg[f];
    }
    __syncthreads();

    const int o = t & 15, ngrp = t >> 4;
    float accl[4] = {0.f, 0.f, 0.f, 0.f};
    float accr[4] = {0.f, 0.f, 0.f, 0.f};
    for (int k4 = 0; k4 < 32; ++k4) {
        float4 w0 = *reinterpret_cast<const float4*>(&wls[o * 132 + 4 * k4]);
        float4 w1 = *reinterpret_cast<const float4*>(&wrs[o * 132 + 4 * k4]);
        #pragma unroll
        for (int j = 0; j < 4; ++j) {
            float4 xv = *reinterpret_cast<const float4*>(&xs[(ngrp + 16 * j) * 132 + 4 * k4]);
            accl[j] += xv.x * w0.x + xv.y * w0.y + xv.z * w0.z + xv.w * w0.w;
            accr[j] += xv.x * w1.x + xv.y * w1.y + xv.z * w1.z + xv.w * w1.w;
        }
    }
    #pragma unroll
    for (int j = 0; j < 4; ++j) {
        long n = base + ngrp + 16 * j;
        xl[n * HID + o] = accl[j];
        xr[n * HID + o] = accr[j];
    }
}

// ---------------------------------------------------------------------------
// k2: edge scatter. thread = (edge, channel). agg[dst][c] += xl[src][c]; cnt[dst]++
// ---------------------------------------------------------------------------
__global__ __launch_bounds__(256) void k2_edges(const int* __restrict__ ei,
                                                const float* __restrict__ xl,
                                                float* __restrict__ agg,
                                                float* __restrict__ cnt) {
    const long tid = (long)blockIdx.x * 256 + threadIdx.x;  // NEDGE*16 threads
    const int e = (int)(tid >> 4);
    const int c = (int)(tid & 15);
    const int s = ei[e];
    const int d = ei[NEDGE + e];
    const float v = xl[(long)s * HID + c];
    atomicAdd(&agg[(long)d * HID + c], v);
    if (c == 0) atomicAdd(&cnt[d], 1.0f);
}

// ---------------------------------------------------------------------------
// k3: out init = b_out broadcast (atomics accumulate partials on top)
// ---------------------------------------------------------------------------
__global__ __launch_bounds__(256) void k3_init_out(const float* __restrict__ bout,
                                                   float* __restrict__ out) {
    int i = blockIdx.x * 256 + threadIdx.x;
    if (i < NG * ODIM) out[i] = bout[i % ODIM];
}

// ---------------------------------------------------------------------------
// k4: fused h = relu(agg/max(cnt,1) + b_l + xr), then skinny GEMM
//     out[g][od] += sum_k h_flat[g][k] * Wout[od][k]  (K split over 512 blocks)
// ---------------------------------------------------------------------------
__global__ __launch_bounds__(256) void k4_out(const float* __restrict__ agg,
                                              const float* __restrict__ cnt,
                                              const float* __restrict__ xr,
                                              const float* __restrict__ bl,
                                              const float* __restrict__ Wout,
                                              float* __restrict__ out) {
    __shared__ float hs[32 * 128];     // [g][kk], broadcast reads -> no pad needed
    __shared__ float wt[39 * 132];     // [od][kk] pad 128->132
    const int t = threadIdx.x;
    const int kbase = blockIdx.x * 128;   // grid = 65536/128 = 512

    // h tile: 32 graphs x 128 cols, computed on the fly
    #pragma unroll
    for (int r = 0; r < 16; ++r) {
        int idx = r * 256 + t;         // 0..4095
        int g = idx >> 7, kk = idx & 127;
        long flat = (long)g * (NODES * HID) + kbase + kk;  // agg/xr are h_flat layout
        float a = agg[flat];
        float xv = xr[flat];
        float cn = cnt[(g << 12) + ((kbase + kk) >> 4)];
        float h = a / fmaxf(cn, 1.0f) + bl[kk & 15] + xv;  // kbase % 16 == 0
        hs[g * 128 + kk] = fmaxf(h, 0.0f);
    }
    // W tile: 39 x 128
    for (int idx = t; idx < ODIM * 128; idx += 256) {
        int od = idx >> 7, kk = idx & 127;
        wt[od * 132 + kk] = Wout[(long)od * (NODES * HID) + kbase + kk];
    }
    __syncthreads();

    const int tod = t & 31, tg = t >> 5;          // tg in 0..7 -> 4 graphs each
    const int od0 = tod;
    const bool has1 = (tod + 32) < ODIM;
    const int od1 = has1 ? tod + 32 : tod;        // clamp (discard later)
    float acc0[4] = {0.f, 0.f, 0.f, 0.f};
    float acc1[4] = {0.f, 0.f, 0.f, 0.f};
    for (int k4 = 0; k4 < 32; ++k4) {
        float4 w0 = *reinterpret_cast<const float4*>(&wt[od0 * 132 + 4 * k4]);
        float4 w1 = *reinterpret_cast<const float4*>(&wt[od1 * 132 + 4 * k4]);
        #pragma unroll
        for (int j = 0; j < 4; ++j) {
            float4 h4 = *reinterpret_cast<const float4*>(&hs[(tg * 4 + j) * 128 + 4 * k4]);
            acc0[j] += h4.x * w0.x + h4.y * w0.y + h4.z * w0.z + h4.w * w0.w;
            acc1[j] += h4.x * w1.x + h4.y * w1.y + h4.z * w1.z + h4.w * w1.w;
        }
    }
    #pragma unroll
    for (int j = 0; j < 4; ++j) {
        int g = tg * 4 + j;
        atomicAdd(&out[g * ODIM + od0], acc0[j]);
        if (has1) atomicAdd(&out[g * ODIM + od1], acc1[j]);
    }
}

// ---------------------------------------------------------------------------
extern "C" void kernel_launch(void* const* d_in, const int* in_sizes, int n_in,
                              void* d_out, int out_size, void* d_ws, size_t ws_size,
                              hipStream_t stream) {
    const float* x    = (const float*)d_in[0];
    const int*   ei   = (const int*)d_in[1];
    const float* Wl   = (const float*)d_in[2];
    const float* bl   = (const float*)d_in[3];
    const float* Wr   = (const float*)d_in[4];
    const float* Wout = (const float*)d_in[5];
    const float* bout = (const float*)d_in[6];
    float* out = (float*)d_out;
    float* ws  = (float*)d_ws;

    float* xl  = ws + WS_XL;
    float* xr  = ws + WS_XR;
    float* agg = ws + WS_AGG;
    float* cnt = ws + WS_CNT;

    // zero agg + cnt (poisoned 0xAA otherwise; harness does not re-poison)
    hipMemsetAsync(agg, 0, (size_t)(NTOT * HID + NTOT) * sizeof(float), stream);

    k1_lin<<<NTOT / 64, 256, 0, stream>>>(x, Wl, Wr, xl, xr);
    k2_edges<<<(long)NEDGE * 16 / 256, 256, 0, stream>>>(ei, xl, agg, cnt);
    k3_init_out<<<(NG * ODIM + 255) / 256, 256, 0, stream>>>(bout, out);
    k4_out<<<(NODES * HID) / 128, 256, 0, stream>>>(agg, cnt, xr, bl, Wout, out);
}

// Round 2
// 457.715 us; speedup vs baseline: 1.0581x; 1.0581x over previous
//
#include <hip/hip_runtime.h>

#define NG 32
#define NODES 4096
#define NTOT (NG * NODES)      // 131072
#define DIN 128
#define HID 16
#define ODIM 39
#define NEDGE (NTOT * 32)      // 4194304
#define EPG (NEDGE / NG)       // 131072 edges per graph

typedef unsigned int uint;

// ws layout (floats) — fast path
#define WS_XL    0
#define WS_XR    2097152
#define WS_AGG   4194304
#define WS_CNT   6291456
#define WS_PEDGE 6422528            // uint[NEDGE]
#define WS_NEED  ((size_t)(6422528 + NEDGE) * 4)   // ~42.5 MB

// ---------------------------------------------------------------------------
// k1: xl = x @ Wl^T, xr = x @ Wr^T   (fused, one pass over x)
// ---------------------------------------------------------------------------
__global__ __launch_bounds__(256) void k1_lin(const float* __restrict__ x,
                                              const float* __restrict__ Wl,
                                              const float* __restrict__ Wr,
                                              float* __restrict__ xl,
                                              float* __restrict__ xr) {
    __shared__ float xs[64 * 132];
    __shared__ float wls[16 * 132];
    __shared__ float wrs[16 * 132];
    const int t = threadIdx.x;

    #pragma unroll
    for (int i = 0; i < 2; ++i) {
        int f = i * 256 + t;
        int o = f >> 5, k4 = f & 31;
        float4 a = reinterpret_cast<const float4*>(Wl)[f];
        float4 b = reinterpret_cast<const float4*>(Wr)[f];
        *reinterpret_cast<float4*>(&wls[o * 132 + 4 * k4]) = a;
        *reinterpret_cast<float4*>(&wrs[o * 132 + 4 * k4]) = b;
    }

    const long base = (long)blockIdx.x * 64;
    const float4* xg = reinterpret_cast<const float4*>(x) + base * 32;
    #pragma unroll
    for (int i = 0; i < 8; ++i) {
        int f = i * 256 + t;
        int n = f >> 5, k4 = f & 31;
        *reinterpret_cast<float4*>(&xs[n * 132 + 4 * k4]) = xg[f];
    }
    __syncthreads();

    const int o = t & 15, ngrp = t >> 4;
    float accl[4] = {0.f, 0.f, 0.f, 0.f};
    float accr[4] = {0.f, 0.f, 0.f, 0.f};
    for (int k4 = 0; k4 < 32; ++k4) {
        float4 w0 = *reinterpret_cast<const float4*>(&wls[o * 132 + 4 * k4]);
        float4 w1 = *reinterpret_cast<const float4*>(&wrs[o * 132 + 4 * k4]);
        #pragma unroll
        for (int j = 0; j < 4; ++j) {
            float4 xv = *reinterpret_cast<const float4*>(&xs[(ngrp + 16 * j) * 132 + 4 * k4]);
            accl[j] += xv.x * w0.x + xv.y * w0.y + xv.z * w0.z + xv.w * w0.w;
            accr[j] += xv.x * w1.x + xv.y * w1.y + xv.z * w1.z + xv.w * w1.w;
        }
    }
    #pragma unroll
    for (int j = 0; j < 4; ++j) {
        long n = base + ngrp + 16 * j;
        xl[n * HID + o] = accl[j];
        xr[n * HID + o] = accr[j];
    }
}

// ---------------------------------------------------------------------------
// kT: repack edge_index (graph g owns edges e == g mod 32) into per-graph
//     contiguous uint words: pedge[g*EPG + idx] = src_local | dst_local<<16.
//     LDS transpose, 129-padded -> conflict-free; coalesced in and out.
// ---------------------------------------------------------------------------
__global__ __launch_bounds__(512) void kT_pack(const int* __restrict__ ei,
                                               uint* __restrict__ pedge) {
    __shared__ uint st[32 * 129];
    const int b = blockIdx.x;       // 1024 blocks x 4096 edges
    const int t = threadIdx.x;
    const int e0 = b * 4096;
    #pragma unroll
    for (int j = 0; j < 8; ++j) {
        int e = e0 + j * 512 + t;
        uint s = (uint)ei[e] & 4095u;
        uint d = (uint)ei[NEDGE + e] & 4095u;
        int g = e & 31;
        int i = (e >> 5) & 127;
        st[g * 129 + i] = s | (d << 16);
    }
    __syncthreads();
    #pragma unroll
    for (int j = 0; j < 8; ++j) {
        int o = j * 512 + t;
        int g = o >> 7, i = o & 127;
        pedge[(size_t)g * EPG + b * 128 + i] = st[g * 129 + i];
    }
}

// ---------------------------------------------------------------------------
// k2 (new): block = (graph, channel-half, node-quarter). Scan graph's packed
// edges coalesced; filter dst to our 1024-node range; gather 32B of xl[src];
// accumulate via LDS atomics; coalesced exclusive store to agg/cnt.
// ---------------------------------------------------------------------------
__global__ __launch_bounds__(1024) void k2_scatter(const uint* __restrict__ pedge,
                                                   const float* __restrict__ xl,
                                                   float* __restrict__ agg,
                                                   float* __restrict__ cnt) {
    __shared__ float lagg[1024 * 8];
    __shared__ float lcnt[1024];
    const int b = blockIdx.x;             // 256 = 32g * 2hf * 4nq
    const int g = b >> 3, hf = (b >> 2) & 1, nq = b & 3;
    const int t = threadIdx.x;

    #pragma unroll
    for (int i = 0; i < 8; ++i) lagg[i * 1024 + t] = 0.f;
    lcnt[t] = 0.f;
    __syncthreads();

    const uint* pe = pedge + (size_t)g * EPG;
    const float* xg = xl + (((size_t)g << 12) * HID) + hf * 8;
    #pragma unroll 2
    for (int it = 0; it < EPG / 1024; ++it) {
        uint ed = pe[it * 1024 + t];
        int sl = ed & 0xFFFF;
        int dl = ed >> 16;
        if ((dl >> 10) == nq) {
            const float4* xp = reinterpret_cast<const float4*>(xg + sl * HID);
            float4 v0 = xp[0];
            float4 v1 = xp[1];
            float* lp = &lagg[(dl & 1023) * 8];
            atomicAdd(lp + 0, v0.x); atomicAdd(lp + 1, v0.y);
            atomicAdd(lp + 2, v0.z); atomicAdd(lp + 3, v0.w);
            atomicAdd(lp + 4, v1.x); atomicAdd(lp + 5, v1.y);
            atomicAdd(lp + 6, v1.z); atomicAdd(lp + 7, v1.w);
            if (hf == 0) atomicAdd(&lcnt[dl & 1023], 1.f);
        }
    }
    __syncthreads();

    // exclusive region -> plain coalesced stores
    float* ga = agg + (((size_t)g << 12) + nq * 1024 + t) * HID + hf * 8;
    *reinterpret_cast<float4*>(ga)     = *reinterpret_cast<float4*>(&lagg[t * 8]);
    *reinterpret_cast<float4*>(ga + 4) = *reinterpret_cast<float4*>(&lagg[t * 8 + 4]);
    if (hf == 0) cnt[((size_t)g << 12) + nq * 1024 + t] = lcnt[t];
}

// ---------------------------------------------------------------------------
// k2 (fallback, small ws): global-atomic scatter
// ---------------------------------------------------------------------------
__global__ __launch_bounds__(256) void k2_edges(const int* __restrict__ ei,
                                                const float* __restrict__ xl,
                                                float* __restrict__ agg,
                                                float* __restrict__ cnt) {
    const long tid = (long)blockIdx.x * 256 + threadIdx.x;
    const int e = (int)(tid >> 4);
    const int c = (int)(tid & 15);
    const int s = ei[e];
    const int d = ei[NEDGE + e];
    const float v = xl[(long)s * HID + c];
    atomicAdd(&agg[(long)d * HID + c], v);
    if (c == 0) atomicAdd(&cnt[d], 1.0f);
}

// ---------------------------------------------------------------------------
__global__ __launch_bounds__(256) void k3_init_out(const float* __restrict__ bout,
                                                   float* __restrict__ out) {
    int i = blockIdx.x * 256 + threadIdx.x;
    if (i < NG * ODIM) out[i] = bout[i % ODIM];
}

// ---------------------------------------------------------------------------
// k4: fused h = relu(agg/max(cnt,1) + b_l + xr), skinny GEMM, K-split + atomics
// ---------------------------------------------------------------------------
__global__ __launch_bounds__(256) void k4_out(const float* __restrict__ agg,
                                              const float* __restrict__ cnt,
                                              const float* __restrict__ xr,
                                              const float* __restrict__ bl,
                                              const float* __restrict__ Wout,
                                              float* __restrict__ out) {
    __shared__ float hs[32 * 128];
    __shared__ float wt[39 * 132];
    const int t = threadIdx.x;
    const int kbase = blockIdx.x * 128;

    #pragma unroll
    for (int r = 0; r < 16; ++r) {
        int idx = r * 256 + t;
        int g = idx >> 7, kk = idx & 127;
        long flat = (long)g * (NODES * HID) + kbase + kk;
        float a = agg[flat];
        float xv = xr[flat];
        float cn = cnt[(g << 12) + ((kbase + kk) >> 4)];
        float h = a / fmaxf(cn, 1.0f) + bl[kk & 15] + xv;
        hs[g * 128 + kk] = fmaxf(h, 0.0f);
    }
    for (int idx = t; idx < ODIM * 128; idx += 256) {
        int od = idx >> 7, kk = idx & 127;
        wt[od * 132 + kk] = Wout[(long)od * (NODES * HID) + kbase + kk];
    }
    __syncthreads();

    const int tod = t & 31, tg = t >> 5;
    const int od0 = tod;
    const bool has1 = (tod + 32) < ODIM;
    const int od1 = has1 ? tod + 32 : tod;
    float acc0[4] = {0.f, 0.f, 0.f, 0.f};
    float acc1[4] = {0.f, 0.f, 0.f, 0.f};
    for (int k4 = 0; k4 < 32; ++k4) {
        float4 w0 = *reinterpret_cast<const float4*>(&wt[od0 * 132 + 4 * k4]);
        float4 w1 = *reinterpret_cast<const float4*>(&wt[od1 * 132 + 4 * k4]);
        #pragma unroll
        for (int j = 0; j < 4; ++j) {
            float4 h4 = *reinterpret_cast<const float4*>(&hs[(tg * 4 + j) * 128 + 4 * k4]);
            acc0[j] += h4.x * w0.x + h4.y * w0.y + h4.z * w0.z + h4.w * w0.w;
            acc1[j] += h4.x * w1.x + h4.y * w1.y + h4.z * w1.z + h4.w * w1.w;
        }
    }
    #pragma unroll
    for (int j = 0; j < 4; ++j) {
        int g = tg * 4 + j;
        atomicAdd(&out[g * ODIM + od0], acc0[j]);
        if (has1) atomicAdd(&out[g * ODIM + od1], acc1[j]);
    }
}

// ---------------------------------------------------------------------------
extern "C" void kernel_launch(void* const* d_in, const int* in_sizes, int n_in,
                              void* d_out, int out_size, void* d_ws, size_t ws_size,
                              hipStream_t stream) {
    const float* x    = (const float*)d_in[0];
    const int*   ei   = (const int*)d_in[1];
    const float* Wl   = (const float*)d_in[2];
    const float* bl   = (const float*)d_in[3];
    const float* Wr   = (const float*)d_in[4];
    const float* Wout = (const float*)d_in[5];
    const float* bout = (const float*)d_in[6];
    float* out = (float*)d_out;
    float* ws  = (float*)d_ws;

    float* xl  = ws + WS_XL;
    float* xr  = ws + WS_XR;
    float* agg = ws + WS_AGG;
    float* cnt = ws + WS_CNT;

    if (ws_size >= WS_NEED) {
        uint* pedge = (uint*)(ws + WS_PEDGE);
        k1_lin<<<NTOT / 64, 256, 0, stream>>>(x, Wl, Wr, xl, xr);
        kT_pack<<<NEDGE / 4096, 512, 0, stream>>>(ei, pedge);
        k2_scatter<<<NG * 2 * 4, 1024, 0, stream>>>(pedge, xl, agg, cnt);
        k3_init_out<<<(NG * ODIM + 255) / 256, 256, 0, stream>>>(bout, out);
        k4_out<<<(NODES * HID) / 128, 256, 0, stream>>>(agg, cnt, xr, bl, Wout, out);
    } else {
        // fallback: global-atomic path (ws too small for pedge)
        hipMemsetAsync(agg, 0, (size_t)(NTOT * HID + NTOT) * sizeof(float), stream);
        k1_lin<<<NTOT / 64, 256, 0, stream>>>(x, Wl, Wr, xl, xr);
        k2_edges<<<(long)NEDGE * 16 / 256, 256, 0, stream>>>(ei, xl, agg, cnt);
        k3_init_out<<<(NG * ODIM + 255) / 256, 256, 0, stream>>>(bout, out);
        k4_out<<<(NODES * HID) / 128, 256, 0, stream>>>(agg, cnt, xr, bl, Wout, out);
    }
}